// Round 18
// baseline (202.532 us; speedup 1.0000x reference)
//
#include <hip/hip_runtime.h>
#include <hip/hip_bf16.h>
#include <stdint.h>

// KipfMLPGNN: B=32, N=64 nodes, D=128, H=256, L=3 layers.
// v18 = v16 fusion with 512-thread blocks (8 waves): occupancy 8->16
// waves/CU with NO extra duplication. 8 waves = (r-half rh = w>>2) x
// (d-slice wl = w&3, 32 d each). T-GEMM: each wave computes h-slice
// [w*32,(w+1)*32) of Ts (all 64 c) + Tr (block's 8 r). Edge: wave does
// 4 r x 32 d, nt=2 amortizes a-build. v17 post-mortem: operand-swap
// register tile -> VGPR 180 -> occ 10.7% (reverted); conflicts ~2% (minor).

#define NB 32
#define NN 64
#define DD 128
#define HH 256

typedef __attribute__((ext_vector_type(4))) float f32x4;
typedef __attribute__((ext_vector_type(8))) _Float16 f16x8;

__device__ __forceinline__ uint64_t cvt4h(f32x4 v) {
  union { _Float16 h[4]; uint64_t u; } x;
  x.h[0] = (_Float16)v[0]; x.h[1] = (_Float16)v[1];
  x.h[2] = (_Float16)v[2]; x.h[3] = (_Float16)v[3];
  return x.u;
}

// Fused setup: gather E0 (256 blk) | W1/W2 -> fp16 (192 blk)
__global__ __launch_bounds__(256) void k_setup(const int* __restrict__ x,
                                               const float* __restrict__ table,
                                               float* __restrict__ E0,
                                               const float* __restrict__ W1_0,
                                               const float* __restrict__ W1_1,
                                               const float* __restrict__ W2_0,
                                               const float* __restrict__ W2_1,
                                               _Float16* __restrict__ W1fp,
                                               _Float16* __restrict__ W2fp) {
  int bid = blockIdx.x, t = threadIdx.x;
  if (bid < 256) {
    int i = bid * 256 + t;
    int node = i >> 5;
    ((f32x4*)E0)[i] = ((const f32x4*)table)[(size_t)x[node] * 32 + (i & 31)];
  } else {
    int tid = (bid - 256) * 256 + t;     // 49152 f32x4 chunks
    const float* src; uint64_t* dst; int off;
    if (tid < 32768) {
      src = (tid < 16384) ? W1_0 : W1_1;
      off = tid & 16383;
      dst = (uint64_t*)W1fp + (tid >> 14) * 16384 + off;
    } else {
      int t2 = tid - 32768;
      src = (t2 < 8192) ? W2_0 : W2_1;
      off = t2 & 8191;
      dst = (uint64_t*)W2fp + (t2 >> 13) * 8192 + off;
    }
    *dst = cvt4h(((const f32x4*)src)[off]);
  }
}

// k_fused<NSP,NR>: grid (8 or 1, 32, 2) = (rg, b, p), 512 threads / 8 waves.
// NSP = prior Sp generations folded into E'. NR = r's per block (8 or 1).
template <int NSP, int NR>
__global__ __launch_bounds__(512) void k_fused(
    const float* __restrict__ E0,
    const float* __restrict__ spA,
    const float* __restrict__ spB,
    float* __restrict__ spOut,
    const _Float16* __restrict__ W1fp,
    const _Float16* __restrict__ W2fp,
    const float* __restrict__ b1_0, const float* __restrict__ b1_1,
    const float* __restrict__ b2_0, const float* __restrict__ b2_1,
    const int* __restrict__ arcs) {
  __shared__ char lds[53248];
  char* Els = lds;            // [64 node][256 B] E' f16, swizzled
  char* Tsl = lds + 16384;    // [64 c][512 B]    Ts f16, swizzled
  char* Trl = lds + 49152;    // [8 r][512 B]     Tr f16 (+b1), swizzled

  constexpr int NRW = (NR == 8) ? 4 : 1;   // r's per wave
  constexpr int DNT = (NR == 8) ? 2 : 1;   // d 16-tiles per wave

  int t = threadIdx.x;
  int rg = blockIdx.x, b = blockIdx.y, p = blockIdx.z;
  int rbase = rg * NR;
  int lane = t & 63, w = t >> 6, col = lane & 15, khi = lane >> 4;
  int rh = (NR == 8) ? (w >> 2) : 0;
  int wl = (NR == 8) ? (w & 3) : w;
  int d0 = wl * (DNT * 16) + col;
  const f32x4 z4 = {0.f, 0.f, 0.f, 0.f};

  // ---- phase 1: stage E' = E0 [+ SpA] [+ SpB] -> Els (f16, swizzled) ----
  {
    const f32x4* e0 = (const f32x4*)(E0 + (size_t)b * NN * DD);
    const f32x4* a0 = (const f32x4*)(spA + (size_t)b * NN * DD);
    const f32x4* a1 = (const f32x4*)(spA + (size_t)(NB + b) * NN * DD);
    const f32x4* c0 = (const f32x4*)(spB + (size_t)b * NN * DD);
    const f32x4* c1 = (const f32x4*)(spB + (size_t)(NB + b) * NN * DD);
#pragma unroll
    for (int ii = 0; ii < 4; ++ii) {
      int idx = ii * 512 + t;          // node=idx>>5, ck=idx&31
      f32x4 v = e0[idx];
      if (NSP >= 1) v += a0[idx] + a1[idx];
      if (NSP >= 2) v += c0[idx] + c1[idx];
      int node = idx >> 5, ck = idx & 31;
      *(uint64_t*)(Els + node * 256 + ((ck * 8) ^ ((node & 7) << 4))) = cvt4h(v);
    }
  }
  __syncthreads();

  // ---- phase 2: T-GEMM. Wave w: h-slice [w*32, w*32+32) ----
  const _Float16* Wq = W1fp + p * 65536;     // [256 h][256 in]
  const float* b1p = p ? b1_1 : b1_0;
  int g = (NR == 8) ? (rg >> 1) : 0;         // node-group holding block's r's
  int sel = (NR == 8) ? (rg & 1) : 0;

  f32x4 taccS[4][2];
  f32x4 taccR[2] = {z4, z4};
#pragma unroll
  for (int mt = 0; mt < 4; ++mt) { taccS[mt][0] = z4; taccS[mt][1] = z4; }
  {
    f16x8 bfr[2][4], bfrR[2][4];
#pragma unroll
    for (int nt = 0; nt < 2; ++nt) {
      int h = w * 32 + nt * 16 + col;
#pragma unroll
      for (int ks = 0; ks < 4; ++ks) {
        bfr[nt][ks]  = *(const f16x8*)(Wq + h * 256 + ks * 32 + khi * 8);
        bfrR[nt][ks] = *(const f16x8*)(Wq + h * 256 + 128 + ks * 32 + khi * 8);
      }
    }
#pragma unroll
    for (int ks = 0; ks < 4; ++ks) {
      f16x8 a[4];
#pragma unroll
      for (int mt = 0; mt < 4; ++mt) {
        int c = mt * 16 + col;
        a[mt] = *(const f16x8*)(Els + c * 256 + ((ks * 64 + khi * 16) ^ ((c & 7) << 4)));
      }
#pragma unroll
      for (int mt = 0; mt < 4; ++mt) {
        taccS[mt][0] = __builtin_amdgcn_mfma_f32_16x16x32_f16(a[mt], bfr[0][ks],
                                                              taccS[mt][0], 0, 0, 0);
        taccS[mt][1] = __builtin_amdgcn_mfma_f32_16x16x32_f16(a[mt], bfr[1][ks],
                                                              taccS[mt][1], 0, 0, 0);
      }
      taccR[0] = __builtin_amdgcn_mfma_f32_16x16x32_f16(a[g], bfrR[0][ks],
                                                        taccR[0], 0, 0, 0);
      taccR[1] = __builtin_amdgcn_mfma_f32_16x16x32_f16(a[g], bfrR[1][ks],
                                                        taccR[1], 0, 0, 0);
    }
  }
  __syncthreads();   // Els reads complete (Tsl separate; barrier orders phases)

  // ---- phase 3: write Ts/Tr to LDS ----
#pragma unroll
  for (int mt = 0; mt < 4; ++mt)
#pragma unroll
    for (int nt = 0; nt < 2; ++nt) {
      int h = w * 32 + nt * 16 + col;
#pragma unroll
      for (int j = 0; j < 4; ++j) {
        int c = mt * 16 + khi * 4 + j;
        *(_Float16*)(Tsl + c * 512 + ((h * 2) ^ ((c & 7) << 4))) =
            (_Float16)taccS[mt][nt][j];
      }
    }
  if ((khi >> 1) == sel) {
#pragma unroll
    for (int nt = 0; nt < 2; ++nt) {
      int h = w * 32 + nt * 16 + col;
      float bb = b1p[h];
#pragma unroll
      for (int j = 0; j < 4; ++j) {
        int lr = (khi & 1) * 4 + j;
        *(_Float16*)(Trl + lr * 512 + ((h * 2) ^ ((lr & 7) << 4))) =
            (_Float16)(taccR[nt][j] + bb);
      }
    }
  }
  __syncthreads();

  // ---- phase 4: edge loop, wave = (rh, wl): NRW r's x DNT*16 d ----
  const _Float16* W2p = W2fp + p * 32768;
  f16x8 bv[DNT][8];
#pragma unroll
  for (int nt = 0; nt < DNT; ++nt)
#pragma unroll
    for (int ks = 0; ks < 8; ++ks)
      bv[nt][ks] = *(const f16x8*)(W2p + (d0 + nt * 16) * 256 + ks * 32 + khi * 8);
  const float* b2p = p ? b2_1 : b2_0;
  float b2v[DNT];
#pragma unroll
  for (int nt = 0; nt < DNT; ++nt) b2v[nt] = b2p[d0 + nt * 16];

#pragma unroll 1
  for (int r = 0; r < NRW; ++r) {
    int lrr = rh * 4 + r;
    f32x4 acc[4][DNT];
#pragma unroll
    for (int mt = 0; mt < 4; ++mt)
#pragma unroll
      for (int nt = 0; nt < DNT; ++nt) acc[mt][nt] = z4;
#pragma unroll
    for (int ks = 0; ks < 8; ++ks) {
      f16x8 trv = *(const f16x8*)(Trl + lrr * 512 +
                                  ((ks * 64 + khi * 16) ^ ((lrr & 7) << 4)));
#pragma unroll
      for (int mt = 0; mt < 4; ++mt) {
        int c = mt * 16 + col;
        f16x8 ts = *(const f16x8*)(Tsl + c * 512 +
                                   ((ks * 64 + khi * 16) ^ ((c & 7) << 4)));
        f16x8 zv = {};
        f16x8 a = __builtin_elementwise_max(ts + trv, zv);
#pragma unroll
        for (int nt = 0; nt < DNT; ++nt)
          acc[mt][nt] = __builtin_amdgcn_mfma_f32_16x16x32_f16(a, bv[nt][ks],
                                                               acc[mt][nt], 0, 0, 0);
      }
    }
    int rr = rbase + lrr;
    const int* arow = arcs + ((size_t)(b * NN + rr)) * NN;
    float s[DNT];
#pragma unroll
    for (int nt = 0; nt < DNT; ++nt) s[nt] = 0.f;
#pragma unroll
    for (int mt = 0; mt < 4; ++mt) {
      const int4 av = *(const int4*)(arow + mt * 16 + khi * 4);
#pragma unroll
      for (int j = 0; j < 4; ++j) {
        int ai = (j == 0) ? av.x : (j == 1) ? av.y : (j == 2) ? av.z : av.w;
        float wgt = p ? (float)ai : 1.0f - (float)ai;
#pragma unroll
        for (int nt = 0; nt < DNT; ++nt)
          s[nt] = fmaf(wgt, fmaxf(acc[mt][nt][j] + b2v[nt], 0.f), s[nt]);
      }
    }
#pragma unroll
    for (int nt = 0; nt < DNT; ++nt) {
      s[nt] += __shfl_xor(s[nt], 16);
      s[nt] += __shfl_xor(s[nt], 32);
    }
    if (khi == 0) {
      float* o = (NR == 1)
          ? spOut + (size_t)(p * NB + b) * DD
          : spOut + ((size_t)(p * NB + b) * NN + rr) * DD;
#pragma unroll
      for (int nt = 0; nt < DNT; ++nt) o[d0 + nt * 16] = s[nt];
    }
  }
}

// out[b][d] = E0[b][0][d] + SpA[0..1] + SpB[0..1] (row 0) + SpC[0..1]
__global__ __launch_bounds__(256) void k_out(const float* __restrict__ E0,
                                             const float* __restrict__ spA,
                                             const float* __restrict__ spB,
                                             const float* __restrict__ spC,
                                             float* __restrict__ out) {
  int i = blockIdx.x * 256 + threadIdx.x;      // 4096
  int b = i >> 7, d = i & 127;
  float acc = E0[(size_t)b * NN * DD + d];
  acc += spA[(size_t)b * NN * DD + d] + spA[(size_t)(NB + b) * NN * DD + d];
  acc += spB[(size_t)b * NN * DD + d] + spB[(size_t)(NB + b) * NN * DD + d];
  acc += spC[(size_t)b * DD + d] + spC[(size_t)(NB + b) * DD + d];
  out[i] = acc;
}

extern "C" void kernel_launch(void* const* d_in, const int* in_sizes, int n_in,
                              void* d_out, int out_size, void* d_ws, size_t ws_size,
                              hipStream_t stream) {
  const int* x       = (const int*)d_in[0];
  const int* arcs    = (const int*)d_in[1];
  const float* table = (const float*)d_in[3];
  const float* W1_0  = (const float*)d_in[4];
  const float* b1_0  = (const float*)d_in[5];
  const float* W2_0  = (const float*)d_in[6];
  const float* b2_0  = (const float*)d_in[7];
  const float* W1_1  = (const float*)d_in[8];
  const float* b1_1  = (const float*)d_in[9];
  const float* W2_1  = (const float*)d_in[10];
  const float* b2_1  = (const float*)d_in[11];
  float* out = (float*)d_out;

  char* ws = (char*)d_ws;
  float* E0        = (float*)ws;                                   // 1 MB
  _Float16* W1fp   = (_Float16*)(ws + (1u << 20));                 // 256 KB
  _Float16* W2fp   = (_Float16*)(ws + (1u << 20) + (256u << 10));  // 128 KB
  float* SpA       = (float*)(ws + (2u << 20));                    // 2 MB
  float* SpB       = (float*)(ws + (4u << 20));                    // 2 MB
  float* SpC       = (float*)(ws + (6u << 20));                    // 32 KB

  k_setup<<<448, 256, 0, stream>>>(x, table, E0, W1_0, W1_1, W2_0, W2_1,
                                   W1fp, W2fp);
  k_fused<0, 8><<<dim3(8, 32, 2), 512, 0, stream>>>(
      E0, E0, E0, SpA, W1fp, W2fp, b1_0, b1_1, b2_0, b2_1, arcs);
  k_fused<1, 8><<<dim3(8, 32, 2), 512, 0, stream>>>(
      E0, SpA, E0, SpB, W1fp, W2fp, b1_0, b1_1, b2_0, b2_1, arcs);
  k_fused<2, 1><<<dim3(1, 32, 2), 512, 0, stream>>>(
      E0, SpA, SpB, SpC, W1fp, W2fp, b1_0, b1_1, b2_0, b2_1, arcs);
  k_out<<<16, 256, 0, stream>>>(E0, SpA, SpB, SpC, out);
}

// Round 19
// 200.389 us; speedup vs baseline: 1.0107x; 1.0107x over previous
//
#include <hip/hip_runtime.h>
#include <hip/hip_bf16.h>
#include <stdint.h>

// KipfMLPGNN: B=32, N=64, D=128, H=256, L=3.
// v19 = v16 (best, 102us) + ABLATION dispatches (template VAR) to locate the
// missing 4x in k_fused (model says ~12us, measures 50us). Real pipeline is
// byte-identical v16 and produces d_out; ablations write to scratch only.
// VAR: 0=full  1=phases1-3 (no edge)  2=no T-GEMM MFMA  3=edge w/o MFMA
// (a sunk via asm, rule #17)  4=edge with ts hoisted once per r.

#define NB 32
#define NN 64
#define DD 128
#define HH 256

typedef __attribute__((ext_vector_type(4))) float f32x4;
typedef __attribute__((ext_vector_type(8))) _Float16 f16x8;

__device__ __forceinline__ uint64_t cvt4h(f32x4 v) {
  union { _Float16 h[4]; uint64_t u; } x;
  x.h[0] = (_Float16)v[0]; x.h[1] = (_Float16)v[1];
  x.h[2] = (_Float16)v[2]; x.h[3] = (_Float16)v[3];
  return x.u;
}

__global__ __launch_bounds__(256) void k_setup(const int* __restrict__ x,
                                               const float* __restrict__ table,
                                               float* __restrict__ E0,
                                               const float* __restrict__ W1_0,
                                               const float* __restrict__ W1_1,
                                               const float* __restrict__ W2_0,
                                               const float* __restrict__ W2_1,
                                               _Float16* __restrict__ W1fp,
                                               _Float16* __restrict__ W2fp) {
  int bid = blockIdx.x, t = threadIdx.x;
  if (bid < 256) {
    int i = bid * 256 + t;
    int node = i >> 5;
    ((f32x4*)E0)[i] = ((const f32x4*)table)[(size_t)x[node] * 32 + (i & 31)];
  } else {
    int tid = (bid - 256) * 256 + t;
    const float* src; uint64_t* dst; int off;
    if (tid < 32768) {
      src = (tid < 16384) ? W1_0 : W1_1;
      off = tid & 16383;
      dst = (uint64_t*)W1fp + (tid >> 14) * 16384 + off;
    } else {
      int t2 = tid - 32768;
      src = (t2 < 8192) ? W2_0 : W2_1;
      off = t2 & 8191;
      dst = (uint64_t*)W2fp + (t2 >> 13) * 8192 + off;
    }
    *dst = cvt4h(((const f32x4*)src)[off]);
  }
}

template <int NSP, int NR, int VAR>
__global__ __launch_bounds__(256) void k_fused(
    const float* __restrict__ E0,
    const float* __restrict__ spA,
    const float* __restrict__ spB,
    float* __restrict__ spOut,
    const _Float16* __restrict__ W1fp,
    const _Float16* __restrict__ W2fp,
    const float* __restrict__ b1_0, const float* __restrict__ b1_1,
    const float* __restrict__ b2_0, const float* __restrict__ b2_1,
    const int* __restrict__ arcs) {
  __shared__ char lds[53248];
  char* Els = lds;
  char* Tsl = lds + 16384;
  char* Trl = lds + 49152;

  int t = threadIdx.x;
  int rg = blockIdx.x, b = blockIdx.y, p = blockIdx.z;
  int rbase = rg * 8;
  int lane = t & 63, w = t >> 6, col = lane & 15, khi = lane >> 4;
  const f32x4 z4 = {0.f, 0.f, 0.f, 0.f};

  // ---- phase 1: stage E' ----
  {
    const f32x4* e0 = (const f32x4*)(E0 + (size_t)b * NN * DD);
    const f32x4* a0 = (const f32x4*)(spA + (size_t)b * NN * DD);
    const f32x4* a1 = (const f32x4*)(spA + (size_t)(NB + b) * NN * DD);
    const f32x4* c0 = (const f32x4*)(spB + (size_t)b * NN * DD);
    const f32x4* c1 = (const f32x4*)(spB + (size_t)(NB + b) * NN * DD);
#pragma unroll
    for (int ii = 0; ii < 8; ++ii) {
      int idx = ii * 256 + t;
      f32x4 v = e0[idx];
      if (NSP >= 1) v += a0[idx] + a1[idx];
      if (NSP >= 2) v += c0[idx] + c1[idx];
      int node = idx >> 5, ck = idx & 31;
      *(uint64_t*)(Els + node * 256 + ((ck * 8) ^ ((node & 7) << 4))) = cvt4h(v);
    }
  }
  __syncthreads();

  // ---- phase 2: T-GEMM ----
  const _Float16* Wq = W1fp + p * 65536;
  const float* b1p = p ? b1_1 : b1_0;
  int g = (NR == 1) ? 0 : (rg >> 1);
  int sel = (NR == 1) ? 0 : (rg & 1);

  f32x4 taccS[4][2];
  f32x4 taccRv[4];
#pragma unroll
  for (int mt = 0; mt < 4; ++mt) { taccS[mt][0] = z4; taccS[mt][1] = z4; taccRv[mt] = z4; }

  if constexpr (VAR != 2) {
#pragma unroll
    for (int nth = 0; nth < 2; ++nth) {
      f16x8 bfr[2][4];
#pragma unroll
      for (int nt = 0; nt < 2; ++nt) {
        int h = w * 64 + nth * 32 + nt * 16 + col;
#pragma unroll
        for (int ks = 0; ks < 4; ++ks)
          bfr[nt][ks] = *(const f16x8*)(Wq + h * 256 + ks * 32 + khi * 8);
      }
      f32x4 tacc[4][2];
#pragma unroll
      for (int mt = 0; mt < 4; ++mt) { tacc[mt][0] = z4; tacc[mt][1] = z4; }
#pragma unroll
      for (int ks = 0; ks < 4; ++ks) {
        f16x8 a[4];
#pragma unroll
        for (int mt = 0; mt < 4; ++mt) {
          int c = mt * 16 + col;
          a[mt] = *(const f16x8*)(Els + c * 256 + ((ks * 64 + khi * 16) ^ ((c & 7) << 4)));
        }
#pragma unroll
        for (int mt = 0; mt < 4; ++mt) {
          tacc[mt][0] = __builtin_amdgcn_mfma_f32_16x16x32_f16(a[mt], bfr[0][ks],
                                                               tacc[mt][0], 0, 0, 0);
          tacc[mt][1] = __builtin_amdgcn_mfma_f32_16x16x32_f16(a[mt], bfr[1][ks],
                                                               tacc[mt][1], 0, 0, 0);
        }
      }
      // write this nth-half directly (matches v16 structure closely enough):
#pragma unroll
      for (int mt = 0; mt < 4; ++mt)
#pragma unroll
        for (int nt = 0; nt < 2; ++nt) {
          int h = w * 64 + nth * 32 + nt * 16 + col;
#pragma unroll
          for (int j = 0; j < 4; ++j) {
            int c = mt * 16 + khi * 4 + j;
            *(_Float16*)(Tsl + c * 512 + ((h * 2) ^ ((c & 7) << 4))) =
                (_Float16)tacc[mt][nt][j];
          }
        }
    }
    {  // Tr
      int mt_t = (NR == 1) ? 0 : (rg >> 1);
#pragma unroll
      for (int nth = 0; nth < 2; ++nth) {
        f16x8 bfr[2][4];
#pragma unroll
        for (int nt = 0; nt < 2; ++nt) {
          int h = w * 64 + nth * 32 + nt * 16 + col;
#pragma unroll
          for (int ks = 0; ks < 4; ++ks)
            bfr[nt][ks] = *(const f16x8*)(Wq + h * 256 + 128 + ks * 32 + khi * 8);
        }
        f32x4 tacc[2] = {z4, z4};
#pragma unroll
        for (int ks = 0; ks < 4; ++ks) {
          f16x8 a = *(const f16x8*)(Els + (mt_t * 16 + col) * 256 +
                                    ((ks * 64 + khi * 16) ^ ((col & 7) << 4)));
          tacc[0] = __builtin_amdgcn_mfma_f32_16x16x32_f16(a, bfr[0][ks], tacc[0], 0, 0, 0);
          tacc[1] = __builtin_amdgcn_mfma_f32_16x16x32_f16(a, bfr[1][ks], tacc[1], 0, 0, 0);
        }
        if ((khi >> 1) == sel) {
#pragma unroll
          for (int nt = 0; nt < 2; ++nt) {
            int h = w * 64 + nth * 32 + nt * 16 + col;
            float bb = b1p[h];
#pragma unroll
            for (int j = 0; j < 4; ++j) {
              int lr = (khi & 1) * 4 + j;
              *(_Float16*)(Trl + lr * 512 + ((h * 2) ^ ((lr & 7) << 4))) =
                  (_Float16)(tacc[nt][j] + bb);
            }
          }
        }
      }
    }
  } else {
    // VAR==2: write zero Ts/Tr (keeps edge-phase inputs defined)
#pragma unroll
    for (int mt = 0; mt < 4; ++mt)
#pragma unroll
      for (int nt = 0; nt < 2; ++nt) {
        int h = w * 64 + nt * 16 + col;  // covers enough; zeros anyway
#pragma unroll
        for (int j = 0; j < 4; ++j) {
          int c = mt * 16 + khi * 4 + j;
          *(_Float16*)(Tsl + c * 512 + ((h * 2) ^ ((c & 7) << 4))) = (_Float16)0.f;
          *(_Float16*)(Tsl + c * 512 + (((h + 128) * 2) ^ ((c & 7) << 4))) = (_Float16)0.f;
        }
      }
    if (t < 8) {
      for (int h = 0; h < 256; ++h)
        *(_Float16*)(Trl + t * 512 + ((h * 2) ^ ((t & 7) << 4))) = (_Float16)0.f;
    }
  }
  __syncthreads();

  if constexpr (VAR == 1) return;   // phases 1-3 measured

  // ---- phase 4: edge ----
  int d0 = w * 32 + col;
  const _Float16* W2p = W2fp + p * 32768;
  f16x8 bv[2][8];
#pragma unroll
  for (int nt = 0; nt < 2; ++nt)
#pragma unroll
    for (int ks = 0; ks < 8; ++ks)
      bv[nt][ks] = *(const f16x8*)(W2p + (d0 + nt * 16) * 256 + ks * 32 + khi * 8);
  const float* b2p = p ? b2_1 : b2_0;
  float b2v[2] = {b2p[d0], b2p[d0 + 16]};

#pragma unroll 1
  for (int r = 0; r < NR; ++r) {
    f32x4 acc[4][2];
#pragma unroll
    for (int mt = 0; mt < 4; ++mt) { acc[mt][0] = z4; acc[mt][1] = z4; }

    f16x8 tsfix[4];
    if constexpr (VAR == 4) {
#pragma unroll
      for (int mt = 0; mt < 4; ++mt) {
        int c = mt * 16 + col;
        tsfix[mt] = *(const f16x8*)(Tsl + c * 512 + ((khi * 16) ^ ((c & 7) << 4)));
      }
    }
#pragma unroll
    for (int ks = 0; ks < 8; ++ks) {
      f16x8 trv = *(const f16x8*)(Trl + r * 512 +
                                  ((ks * 64 + khi * 16) ^ ((r & 7) << 4)));
#pragma unroll
      for (int mt = 0; mt < 4; ++mt) {
        f16x8 ts;
        if constexpr (VAR == 4) {
          ts = tsfix[mt];
        } else {
          int c = mt * 16 + col;
          ts = *(const f16x8*)(Tsl + c * 512 +
                               ((ks * 64 + khi * 16) ^ ((c & 7) << 4)));
        }
        f16x8 zv = {};
        f16x8 a = __builtin_elementwise_max(ts + trv, zv);
        if constexpr (VAR == 3) {
          asm volatile("" :: "v"(a));   // keep a live, no MFMA (rule #17)
        } else {
          acc[mt][0] = __builtin_amdgcn_mfma_f32_16x16x32_f16(a, bv[0][ks],
                                                              acc[mt][0], 0, 0, 0);
          acc[mt][1] = __builtin_amdgcn_mfma_f32_16x16x32_f16(a, bv[1][ks],
                                                              acc[mt][1], 0, 0, 0);
        }
      }
    }
    int rr = rbase + r;
    const int* arow = arcs + ((size_t)(b * NN + rr)) * NN;
    float s0 = 0.f, s1 = 0.f;
#pragma unroll
    for (int mt = 0; mt < 4; ++mt) {
      const int4 av = *(const int4*)(arow + mt * 16 + khi * 4);
#pragma unroll
      for (int j = 0; j < 4; ++j) {
        int ai = (j == 0) ? av.x : (j == 1) ? av.y : (j == 2) ? av.z : av.w;
        float wgt = p ? (float)ai : 1.0f - (float)ai;
        s0 = fmaf(wgt, fmaxf(acc[mt][0][j] + b2v[0], 0.f), s0);
        s1 = fmaf(wgt, fmaxf(acc[mt][1][j] + b2v[1], 0.f), s1);
      }
    }
    s0 += __shfl_xor(s0, 16); s0 += __shfl_xor(s0, 32);
    s1 += __shfl_xor(s1, 16); s1 += __shfl_xor(s1, 32);
    if (khi == 0) {
      if (NR == 1) {
        float* o = spOut + (size_t)(p * NB + b) * DD;
        o[d0] = s0; o[d0 + 16] = s1;
      } else {
        float* o = spOut + ((size_t)(p * NB + b) * NN + rr) * DD;
        o[d0] = s0; o[d0 + 16] = s1;
      }
    }
  }
}

__global__ __launch_bounds__(256) void k_out(const float* __restrict__ E0,
                                             const float* __restrict__ spA,
                                             const float* __restrict__ spB,
                                             const float* __restrict__ spC,
                                             float* __restrict__ out) {
  int i = blockIdx.x * 256 + threadIdx.x;
  int b = i >> 7, d = i & 127;
  float acc = E0[(size_t)b * NN * DD + d];
  acc += spA[(size_t)b * NN * DD + d] + spA[(size_t)(NB + b) * NN * DD + d];
  acc += spB[(size_t)b * NN * DD + d] + spB[(size_t)(NB + b) * NN * DD + d];
  acc += spC[(size_t)b * DD + d] + spC[(size_t)(NB + b) * DD + d];
  out[i] = acc;
}

extern "C" void kernel_launch(void* const* d_in, const int* in_sizes, int n_in,
                              void* d_out, int out_size, void* d_ws, size_t ws_size,
                              hipStream_t stream) {
  const int* x       = (const int*)d_in[0];
  const int* arcs    = (const int*)d_in[1];
  const float* table = (const float*)d_in[3];
  const float* W1_0  = (const float*)d_in[4];
  const float* b1_0  = (const float*)d_in[5];
  const float* W2_0  = (const float*)d_in[6];
  const float* b2_0  = (const float*)d_in[7];
  const float* W1_1  = (const float*)d_in[8];
  const float* b1_1  = (const float*)d_in[9];
  const float* W2_1  = (const float*)d_in[10];
  const float* b2_1  = (const float*)d_in[11];
  float* out = (float*)d_out;

  char* ws = (char*)d_ws;
  float* E0        = (float*)ws;                                   // 1 MB
  _Float16* W1fp   = (_Float16*)(ws + (1u << 20));                 // 256 KB
  _Float16* W2fp   = (_Float16*)(ws + (1u << 20) + (256u << 10));  // 128 KB
  float* SpA       = (float*)(ws + (2u << 20));                    // 2 MB
  float* SpB       = (float*)(ws + (4u << 20));                    // 2 MB
  float* SpC       = (float*)(ws + (6u << 20));                    // 32 KB
  float* SpScr     = (float*)(ws + (8u << 20));                    // 2 MB scratch

  k_setup<<<448, 256, 0, stream>>>(x, table, E0, W1_0, W1_1, W2_0, W2_1,
                                   W1fp, W2fp);
  // ---- real pipeline (v16) ----
  k_fused<0, 8, 0><<<dim3(8, 32, 2), 256, 0, stream>>>(
      E0, E0, E0, SpA, W1fp, W2fp, b1_0, b1_1, b2_0, b2_1, arcs);
  k_fused<1, 8, 0><<<dim3(8, 32, 2), 256, 0, stream>>>(
      E0, SpA, E0, SpB, W1fp, W2fp, b1_0, b1_1, b2_0, b2_1, arcs);
  k_fused<2, 1, 0><<<dim3(1, 32, 2), 256, 0, stream>>>(
      E0, SpA, SpB, SpC, W1fp, W2fp, b1_0, b1_1, b2_0, b2_1, arcs);
  k_out<<<16, 256, 0, stream>>>(E0, SpA, SpB, SpC, out);
  // ---- ablation probes (scratch only; removed next round) ----
  k_fused<0, 8, 1><<<dim3(8, 32, 2), 256, 0, stream>>>(
      E0, E0, E0, SpScr, W1fp, W2fp, b1_0, b1_1, b2_0, b2_1, arcs);
  k_fused<0, 8, 2><<<dim3(8, 32, 2), 256, 0, stream>>>(
      E0, E0, E0, SpScr, W1fp, W2fp, b1_0, b1_1, b2_0, b2_1, arcs);
  k_fused<0, 8, 3><<<dim3(8, 32, 2), 256, 0, stream>>>(
      E0, E0, E0, SpScr, W1fp, W2fp, b1_0, b1_1, b2_0, b2_1, arcs);
  k_fused<0, 8, 4><<<dim3(8, 32, 2), 256, 0, stream>>>(
      E0, E0, E0, SpScr, W1fp, W2fp, b1_0, b1_1, b2_0, b2_1, arcs);
}

// Round 20
// 111.424 us; speedup vs baseline: 1.8177x; 1.7984x over previous
//
#include <hip/hip_runtime.h>
#include <hip/hip_bf16.h>
#include <stdint.h>

// KipfMLPGNN: B=32, N=64, D=128, H=256, L=3.
// v20 = v16 fusion, c-split for occupancy: grid (8 rg, 32 b, 4 z=p*2+ch)
// = 1024 blocks = 4 blocks/CU (v16: 512 = 2/CU). Each block covers 32 c's
// (ch half): Ts-GEMM total FLOPs unchanged (half per block x 2 blocks),
// only Tr-GEMM duplicates (+4%). LDS 53->32KB (stage 32 c-rows + 16 r-rows
// only), edge mt 4->2, acc 32->16 regs. c-sum partials go to slice p*2+ch
// (4 slices/generation), folded on the fly by next layer's staging / k_out.

#define NB 32
#define NN 64
#define DD 128
#define HH 256

typedef __attribute__((ext_vector_type(4))) float f32x4;
typedef __attribute__((ext_vector_type(8))) _Float16 f16x8;

__device__ __forceinline__ uint64_t cvt4h(f32x4 v) {
  union { _Float16 h[4]; uint64_t u; } x;
  x.h[0] = (_Float16)v[0]; x.h[1] = (_Float16)v[1];
  x.h[2] = (_Float16)v[2]; x.h[3] = (_Float16)v[3];
  return x.u;
}

// Fused setup: gather E0 (256 blk) | W1/W2 -> fp16 (192 blk)
__global__ __launch_bounds__(256) void k_setup(const int* __restrict__ x,
                                               const float* __restrict__ table,
                                               float* __restrict__ E0,
                                               const float* __restrict__ W1_0,
                                               const float* __restrict__ W1_1,
                                               const float* __restrict__ W2_0,
                                               const float* __restrict__ W2_1,
                                               _Float16* __restrict__ W1fp,
                                               _Float16* __restrict__ W2fp) {
  int bid = blockIdx.x, t = threadIdx.x;
  if (bid < 256) {
    int i = bid * 256 + t;
    int node = i >> 5;
    ((f32x4*)E0)[i] = ((const f32x4*)table)[(size_t)x[node] * 32 + (i & 31)];
  } else {
    int tid = (bid - 256) * 256 + t;     // 49152 f32x4 chunks
    const float* src; uint64_t* dst; int off;
    if (tid < 32768) {
      src = (tid < 16384) ? W1_0 : W1_1;
      off = tid & 16383;
      dst = (uint64_t*)W1fp + (tid >> 14) * 16384 + off;
    } else {
      int t2 = tid - 32768;
      src = (t2 < 8192) ? W2_0 : W2_1;
      off = t2 & 8191;
      dst = (uint64_t*)W2fp + (t2 >> 13) * 8192 + off;
    }
    *dst = cvt4h(((const f32x4*)src)[off]);
  }
}

// k_fused<NSP,NR>: grid (8 or 1, 32, 4) = (rg, b, z=p*2+ch).
// NSP = prior Sp generations (4 slices each) folded into E'. NR = r's/block.
template <int NSP, int NR>
__global__ __launch_bounds__(256) void k_fused(
    const float* __restrict__ E0,
    const float* __restrict__ spA,
    const float* __restrict__ spB,
    float* __restrict__ spOut,
    const _Float16* __restrict__ W1fp,
    const _Float16* __restrict__ W2fp,
    const float* __restrict__ b1_0, const float* __restrict__ b1_1,
    const float* __restrict__ b2_0, const float* __restrict__ b2_1,
    const int* __restrict__ arcs) {
  __shared__ char lds[32768];
  char* Els_c = lds;            // [32 c-row][256 B]  E' f16, swizzled
  char* Els_r = lds + 8192;     // [16 r-row][256 B]  E' f16, swizzled
  char* Tsl   = lds + 12288;    // [32 c][512 B]      Ts f16, swizzled
  char* Trl   = lds + 28672;    // [8 r][512 B]       Tr f16 (+b1), swizzled

  int t = threadIdx.x;
  int rg = blockIdx.x, b = blockIdx.y;
  int p = blockIdx.z >> 1, ch = blockIdx.z & 1;
  int rbase = rg * NR;
  int lane = t & 63, w = t >> 6, col = lane & 15, khi = lane >> 4;
  const f32x4 z4 = {0.f, 0.f, 0.f, 0.f};

  // ---- phase 1: stage E' rows (32 c of this ch-half + 16 r) ----
  {
    const float* eb = E0 + (size_t)b * NN * DD;
#pragma unroll
    for (int ii = 0; ii < 6; ++ii) {
      int chunk = ii * 256 + t;          // 1536 chunks: lrow=chunk>>5, ck
      int lrow = chunk >> 5, ck = chunk & 31;
      int node; char* dst;
      if (lrow < 32) {
        node = ch * 32 + lrow;
        dst = Els_c + lrow * 256;
      } else {
        int lr = lrow - 32;
        int nr = rbase + lr; if (nr > 63) nr = 63;
        node = nr;
        dst = Els_r + lr * 256;
      }
      f32x4 v = ((const f32x4*)(eb + node * DD))[ck];
      if (NSP >= 1) {
#pragma unroll
        for (int s = 0; s < 4; ++s)
          v += ((const f32x4*)(spA + ((size_t)(s * NB + b) * NN + node) * DD))[ck];
      }
      if (NSP >= 2) {
#pragma unroll
        for (int s = 0; s < 4; ++s)
          v += ((const f32x4*)(spB + ((size_t)(s * NB + b) * NN + node) * DD))[ck];
      }
      *(uint64_t*)(dst + ((ck * 8) ^ ((lrow & 7) << 4))) = cvt4h(v);
    }
  }
  __syncthreads();

  // ---- phase 2: T-GEMM. Wave w owns h-slice [w*64, w*64+64) ----
  const _Float16* Wq = W1fp + p * 65536;     // [256 h][256 in]
  const float* b1p = p ? b1_1 : b1_0;

#pragma unroll
  for (int nth = 0; nth < 2; ++nth) {        // Ts: 32 c x 32 h per pass
    f16x8 bfr[2][4];
#pragma unroll
    for (int nt = 0; nt < 2; ++nt) {
      int h = w * 64 + nth * 32 + nt * 16 + col;
#pragma unroll
      for (int ks = 0; ks < 4; ++ks)
        bfr[nt][ks] = *(const f16x8*)(Wq + h * 256 + ks * 32 + khi * 8);
    }
    f32x4 tacc[2][2];
#pragma unroll
    for (int mt = 0; mt < 2; ++mt) { tacc[mt][0] = z4; tacc[mt][1] = z4; }
#pragma unroll
    for (int ks = 0; ks < 4; ++ks) {
      f16x8 a[2];
#pragma unroll
      for (int mt = 0; mt < 2; ++mt) {
        int c = mt * 16 + col;
        a[mt] = *(const f16x8*)(Els_c + c * 256 +
                                ((ks * 64 + khi * 16) ^ ((c & 7) << 4)));
      }
#pragma unroll
      for (int mt = 0; mt < 2; ++mt) {
        tacc[mt][0] = __builtin_amdgcn_mfma_f32_16x16x32_f16(a[mt], bfr[0][ks],
                                                             tacc[mt][0], 0, 0, 0);
        tacc[mt][1] = __builtin_amdgcn_mfma_f32_16x16x32_f16(a[mt], bfr[1][ks],
                                                             tacc[mt][1], 0, 0, 0);
      }
    }
#pragma unroll
    for (int mt = 0; mt < 2; ++mt)
#pragma unroll
      for (int nt = 0; nt < 2; ++nt) {
        int h = w * 64 + nth * 32 + nt * 16 + col;
#pragma unroll
        for (int j = 0; j < 4; ++j) {
          int c = mt * 16 + khi * 4 + j;
          *(_Float16*)(Tsl + c * 512 + ((h * 2) ^ ((c & 7) << 4))) =
              (_Float16)tacc[mt][nt][j];
        }
      }
  }
#pragma unroll
  for (int nth = 0; nth < 2; ++nth) {        // Tr: 16 r-rows (keep 8) x 32 h
    f16x8 bfrR[2][4];
#pragma unroll
    for (int nt = 0; nt < 2; ++nt) {
      int h = w * 64 + nth * 32 + nt * 16 + col;
#pragma unroll
      for (int ks = 0; ks < 4; ++ks)
        bfrR[nt][ks] = *(const f16x8*)(Wq + h * 256 + 128 + ks * 32 + khi * 8);
    }
    f32x4 taccR[2] = {z4, z4};
#pragma unroll
    for (int ks = 0; ks < 4; ++ks) {
      f16x8 ar = *(const f16x8*)(Els_r + col * 256 +
                                 ((ks * 64 + khi * 16) ^ ((col & 7) << 4)));
      taccR[0] = __builtin_amdgcn_mfma_f32_16x16x32_f16(ar, bfrR[0][ks],
                                                        taccR[0], 0, 0, 0);
      taccR[1] = __builtin_amdgcn_mfma_f32_16x16x32_f16(ar, bfrR[1][ks],
                                                        taccR[1], 0, 0, 0);
    }
    if (khi < 2) {                           // rows 0..7 valid
#pragma unroll
      for (int nt = 0; nt < 2; ++nt) {
        int h = w * 64 + nth * 32 + nt * 16 + col;
        float bb = b1p[h];
#pragma unroll
        for (int j = 0; j < 4; ++j) {
          int lr = khi * 4 + j;
          *(_Float16*)(Trl + lr * 512 + ((h * 2) ^ ((lr & 7) << 4))) =
              (_Float16)(taccR[nt][j] + bb);
        }
      }
    }
  }
  __syncthreads();

  // ---- phase 3: edge loop over NR r's; wave w owns d [w*32, w*32+32) ----
  int d0 = w * 32 + col;
  const _Float16* W2p = W2fp + p * 32768;
  f16x8 bv[2][8];
#pragma unroll
  for (int nt = 0; nt < 2; ++nt)
#pragma unroll
    for (int ks = 0; ks < 8; ++ks)
      bv[nt][ks] = *(const f16x8*)(W2p + (d0 + nt * 16) * 256 + ks * 32 + khi * 8);
  const float* b2p = p ? b2_1 : b2_0;
  float b2v[2] = {b2p[d0], b2p[d0 + 16]};

#pragma unroll 1
  for (int r = 0; r < NR; ++r) {
    f32x4 acc[2][2];
#pragma unroll
    for (int mt = 0; mt < 2; ++mt) { acc[mt][0] = z4; acc[mt][1] = z4; }
#pragma unroll
    for (int ks = 0; ks < 8; ++ks) {
      f16x8 trv = *(const f16x8*)(Trl + r * 512 +
                                  ((ks * 64 + khi * 16) ^ ((r & 7) << 4)));
#pragma unroll
      for (int mt = 0; mt < 2; ++mt) {
        int c = mt * 16 + col;
        f16x8 ts = *(const f16x8*)(Tsl + c * 512 +
                                   ((ks * 64 + khi * 16) ^ ((c & 7) << 4)));
        f16x8 zv = {};
        f16x8 a = __builtin_elementwise_max(ts + trv, zv);
        acc[mt][0] = __builtin_amdgcn_mfma_f32_16x16x32_f16(a, bv[0][ks],
                                                            acc[mt][0], 0, 0, 0);
        acc[mt][1] = __builtin_amdgcn_mfma_f32_16x16x32_f16(a, bv[1][ks],
                                                            acc[mt][1], 0, 0, 0);
      }
    }
    int rr = rbase + r;
    const int* arow = arcs + ((size_t)(b * NN + rr)) * NN + ch * 32;
    float s0 = 0.f, s1 = 0.f;
#pragma unroll
    for (int mt = 0; mt < 2; ++mt) {
      const int4 av = *(const int4*)(arow + mt * 16 + khi * 4);
#pragma unroll
      for (int j = 0; j < 4; ++j) {
        int ai = (j == 0) ? av.x : (j == 1) ? av.y : (j == 2) ? av.z : av.w;
        float wgt = p ? (float)ai : 1.0f - (float)ai;
        s0 = fmaf(wgt, fmaxf(acc[mt][0][j] + b2v[0], 0.f), s0);
        s1 = fmaf(wgt, fmaxf(acc[mt][1][j] + b2v[1], 0.f), s1);
      }
    }
    s0 += __shfl_xor(s0, 16); s0 += __shfl_xor(s0, 32);
    s1 += __shfl_xor(s1, 16); s1 += __shfl_xor(s1, 32);
    if (khi == 0) {
      int slice = p * 2 + ch;
      float* o = (NR == 1)
          ? spOut + (size_t)(slice * NB + b) * DD
          : spOut + ((size_t)(slice * NB + b) * NN + rr) * DD;
      o[d0] = s0; o[d0 + 16] = s1;
    }
  }
}

// out[b][d] = E0[b][0][d] + Sum_s SpA[s][b][0][d] + SpB[s][b][0][d] + SpC[s][b][d]
__global__ __launch_bounds__(256) void k_out(const float* __restrict__ E0,
                                             const float* __restrict__ spA,
                                             const float* __restrict__ spB,
                                             const float* __restrict__ spC,
                                             float* __restrict__ out) {
  int i = blockIdx.x * 256 + threadIdx.x;      // 4096
  int b = i >> 7, d = i & 127;
  float acc = E0[(size_t)b * NN * DD + d];
#pragma unroll
  for (int s = 0; s < 4; ++s) {
    acc += spA[(size_t)(s * NB + b) * NN * DD + d];
    acc += spB[(size_t)(s * NB + b) * NN * DD + d];
    acc += spC[(size_t)(s * NB + b) * DD + d];
  }
  out[i] = acc;
}

extern "C" void kernel_launch(void* const* d_in, const int* in_sizes, int n_in,
                              void* d_out, int out_size, void* d_ws, size_t ws_size,
                              hipStream_t stream) {
  const int* x       = (const int*)d_in[0];
  const int* arcs    = (const int*)d_in[1];
  const float* table = (const float*)d_in[3];
  const float* W1_0  = (const float*)d_in[4];
  const float* b1_0  = (const float*)d_in[5];
  const float* W2_0  = (const float*)d_in[6];
  const float* b2_0  = (const float*)d_in[7];
  const float* W1_1  = (const float*)d_in[8];
  const float* b1_1  = (const float*)d_in[9];
  const float* W2_1  = (const float*)d_in[10];
  const float* b2_1  = (const float*)d_in[11];
  float* out = (float*)d_out;

  char* ws = (char*)d_ws;
  float* E0        = (float*)ws;                                   // 1 MB
  _Float16* W1fp   = (_Float16*)(ws + (1u << 20));                 // 256 KB
  _Float16* W2fp   = (_Float16*)(ws + (1u << 20) + (256u << 10));  // 128 KB
  float* SpA       = (float*)(ws + (2u << 20));                    // 4 MB
  float* SpB       = (float*)(ws + (6u << 20));                    // 4 MB
  float* SpC       = (float*)(ws + (10u << 20));                   // 64 KB

  k_setup<<<448, 256, 0, stream>>>(x, table, E0, W1_0, W1_1, W2_0, W2_1,
                                   W1fp, W2fp);
  k_fused<0, 8><<<dim3(8, 32, 4), 256, 0, stream>>>(
      E0, E0, E0, SpA, W1fp, W2fp, b1_0, b1_1, b2_0, b2_1, arcs);
  k_fused<1, 8><<<dim3(8, 32, 4), 256, 0, stream>>>(
      E0, SpA, E0, SpB, W1fp, W2fp, b1_0, b1_1, b2_0, b2_1, arcs);
  k_fused<2, 1><<<dim3(1, 32, 4), 256, 0, stream>>>(
      E0, SpA, SpB, SpC, W1fp, W2fp, b1_0, b1_1, b2_0, b2_1, arcs);
  k_out<<<16, 256, 0, stream>>>(E0, SpA, SpB, SpC, out);
}